// Round 8
// baseline (672.731 us; speedup 1.0000x reference)
//
#include <hip/hip_runtime.h>

#define HSZ 32
#define TSEQ 2048
#define NBATCH 256

typedef unsigned int v2u __attribute__((ext_vector_type(2)));

__device__ __forceinline__ float hw_exp2(float x) {
#if __has_builtin(__builtin_amdgcn_exp2f)
    return __builtin_amdgcn_exp2f(x);
#else
    return exp2f(x);
#endif
}

__device__ __forceinline__ float hw_rcp(float x) {
#if __has_builtin(__builtin_amdgcn_rcpf)
    return __builtin_amdgcn_rcpf(x);
#else
    return 1.0f / x;
#endif
}

__device__ __forceinline__ float readlane_f(float v, int lane) {
    return __uint_as_float(__builtin_amdgcn_readlane(__float_as_uint(v), lane));
}

// Direction-agnostic cross-half combine: returns v[lane&31] + v[(lane&31)+32]
// in ALL lanes, regardless of which way the swap moves halves. (Proven R2-R6.)
__device__ __forceinline__ float half_sum(float v) {
#if __has_builtin(__builtin_amdgcn_permlane32_swap)
    v2u r = __builtin_amdgcn_permlane32_swap(__float_as_uint(v), __float_as_uint(v), false, false);
    return __uint_as_float(r.x) + __uint_as_float(r.y);
#else
    return v + __shfl_xor(v, 32, 64);
#endif
}

#define NL2E -1.44269504088896340736f   // -log2(e)

__global__ __launch_bounds__(64, 1) void lstm_last_kernel(
    const float* __restrict__ x,      // [B, T, 1]
    const float* __restrict__ W_ih,   // [4H, 1]
    const float* __restrict__ W_hh,   // [4H, H]
    const float* __restrict__ b_ih,   // [4H]
    const float* __restrict__ b_hh,   // [4H]
    float* __restrict__ out)          // [B, H]
{
    const int b    = blockIdx.x;
    const int l    = threadIdx.x;   // 0..63
    const int k    = l & 31;        // hidden unit index
    const int half = l >> 5;        // 0: rows (i_k, g_k); 1: rows (f_k, o_k)
    const int row0 = l;             // i_k (half0) or f_k (half1)
    const int row1 = l + 64;        // g_k (half0) or o_k (half1)

    __shared__ float  x_lds[TSEQ + 4];
    // Per-lane weight store: [dot][j/4][lane] float4. Lanes stride 16B ->
    // even bank coverage, no excess conflicts. 16 KB total.
    __shared__ float4 w_lds[2][HSZ / 4][64];

    // ---- one-time staging: x row into LDS (float4, coalesced) ----
    const float4* xrow4 = (const float4*)(x + (size_t)b * TSEQ);
    float4* xl4 = (float4*)x_lds;
    #pragma unroll
    for (int j = 0; j < (TSEQ / 4) / 64; ++j)   // 8 iters
        xl4[j * 64 + l] = xrow4[j * 64 + l];
    if (l == 0) x_lds[TSEQ] = 0.0f;

    // ---- one-time: prescaled weights straight into LDS (never live in regs
    //      across the loop -> the allocator has nothing to bank/remat) ----
    // dot0 (i/f): scale -log2e. dot1: g (tanh=2*sigm(2x)-1) -> -2log2e; o -> -log2e.
    const float sc0 = NL2E;
    const float sc1 = half ? NL2E : 2.0f * NL2E;
    #pragma unroll
    for (int j = 0; j < HSZ; j += 4) {
        float4 a  = *(const float4*)(W_hh + row0 * HSZ + j);
        float4 c4 = *(const float4*)(W_hh + row1 * HSZ + j);
        w_lds[0][j/4][l] = make_float4(a.x  * sc0, a.y  * sc0, a.z  * sc0, a.w  * sc0);
        w_lds[1][j/4][l] = make_float4(c4.x * sc1, c4.y * sc1, c4.z * sc1, c4.w * sc1);
    }
    const float wx0   = W_ih[row0] * sc0;
    const float wx1   = W_ih[row1] * sc1;
    const float bias0 = (b_ih[row0] + b_hh[row0]) * sc0;
    const float bias1 = (b_ih[row1] + b_hh[row1]) * sc1;

    const float s1mul = half ? 1.0f : 2.0f;
    const float s1add = half ? 0.0f : -1.0f;

    float c  = 0.0f;   // cell state
    float hk = 0.0f;   // h_k valid in lanes 32..63

    __syncthreads();
    float xt = x_lds[0];

    #pragma unroll 1
    for (int t = 0; t < TSEQ; ++t) {
        // Memory clobber: weight loads below cannot be CSE'd/hoisted across
        // iterations -> weights are streamed from LDS each step, guaranteed.
        asm volatile("" ::: "memory");

        // ---- broadcast h (lanes 32..63) into 32 wave-uniform SGPRs ----
        float hs[HSZ];
        #pragma unroll
        for (int j = 0; j < HSZ; ++j) hs[j] = readlane_f(hk, 32 + j);

        float xt_next = x_lds[t + 1];   // prefetch, latency hidden under dots

        // ---- two length-32 dots: weights stream from LDS (ds_read_b128),
        //      v_fma_f32 (VGPR weight x SGPR h) ----
        float p00 = fmaf(wx0, xt, bias0), p01 = 0.f, p02 = 0.f, p03 = 0.f;
        float p10 = fmaf(wx1, xt, bias1), p11 = 0.f, p12 = 0.f, p13 = 0.f;
        #pragma unroll
        for (int jg = 0; jg < HSZ / 4; ++jg) {
            float4 wa = w_lds[0][jg][l];
            float4 wb = w_lds[1][jg][l];
            p00 = fmaf(wa.x, hs[4*jg],   p00);
            p01 = fmaf(wa.y, hs[4*jg+1], p01);
            p02 = fmaf(wa.z, hs[4*jg+2], p02);
            p03 = fmaf(wa.w, hs[4*jg+3], p03);
            p10 = fmaf(wb.x, hs[4*jg],   p10);
            p11 = fmaf(wb.y, hs[4*jg+1], p11);
            p12 = fmaf(wb.z, hs[4*jg+2], p12);
            p13 = fmaf(wb.w, hs[4*jg+3], p13);
        }
        float d0 = (p00 + p01) + (p02 + p03);   // i (half0) / f (half1), pre-scaled
        float d1 = (p10 + p11) + (p12 + p13);   // g (half0) / o (half1), pre-scaled

        float a0 = hw_rcp(1.0f + hw_exp2(d0));                     // sigmoid(i/f)
        float a1 = fmaf(s1mul, hw_rcp(1.0f + hw_exp2(d1)), s1add); // tanh(g)/sigm(o)

        // half0 contributes i*g, half1 contributes f*c; cross-half SUM = c_new
        float v  = a0 * (half ? c : a1);
        float cn = half_sum(v);
        c = cn;

        float th = fmaf(2.0f, hw_rcp(1.0f + hw_exp2(cn * (2.0f * NL2E))), -1.0f); // tanh(c)
        hk = a1 * th;   // valid (o * tanh(c)) in lanes 32..63

        xt = xt_next;
    }

    if (half) out[b * HSZ + k] = hk;
}

extern "C" void kernel_launch(void* const* d_in, const int* in_sizes, int n_in,
                              void* d_out, int out_size, void* d_ws, size_t ws_size,
                              hipStream_t stream) {
    const float* x    = (const float*)d_in[0];
    const float* W_ih = (const float*)d_in[1];
    const float* W_hh = (const float*)d_in[2];
    const float* b_ih = (const float*)d_in[3];
    const float* b_hh = (const float*)d_in[4];
    float* out = (float*)d_out;

    lstm_last_kernel<<<NBATCH, 64, 0, stream>>>(x, W_ih, W_hh, b_ih, b_hh, out);
}

// Round 9
// 384.794 us; speedup vs baseline: 1.7483x; 1.7483x over previous
//
#include <hip/hip_runtime.h>

#define HSZ 32
#define TSEQ 2048
#define NBATCH 256

typedef float v2f __attribute__((ext_vector_type(2)));
typedef unsigned int v2u __attribute__((ext_vector_type(2)));

__device__ __forceinline__ v2f make2(float a, float b) {
    v2f r; r.x = a; r.y = b; return r;
}

__device__ __forceinline__ float hw_exp2(float x) {
#if __has_builtin(__builtin_amdgcn_exp2f)
    return __builtin_amdgcn_exp2f(x);
#else
    return exp2f(x);
#endif
}

__device__ __forceinline__ float hw_rcp(float x) {
#if __has_builtin(__builtin_amdgcn_rcpf)
    return __builtin_amdgcn_rcpf(x);
#else
    return 1.0f / x;
#endif
}

// Direction-agnostic cross-half combine: returns v[lane&31] + v[(lane&31)+32]
// in ALL lanes, regardless of which way the swap moves halves. (Proven R2-R7.)
__device__ __forceinline__ float half_sum(float v) {
#if __has_builtin(__builtin_amdgcn_permlane32_swap)
    v2u r = __builtin_amdgcn_permlane32_swap(__float_as_uint(v), __float_as_uint(v), false, false);
    return __uint_as_float(r.x) + __uint_as_float(r.y);
#else
    return v + __shfl_xor(v, 32, 64);
#endif
}

#if __has_builtin(__builtin_elementwise_fma)
#define PKFMA(a, b, cc) __builtin_elementwise_fma((a), (b), (cc))
#else
__device__ __forceinline__ v2f PKFMA(v2f a, v2f b, v2f c) {
    return make2(fmaf(a.x, b.x, c.x), fmaf(a.y, b.y, c.y));
}
#endif

#define NL2E -1.44269504088896340736f   // -log2(e)
// Carried cell state is pre-scaled: cc = 2*log2e * c, so tanh(c) = 1 - 2*rcp(1+exp2(cc)).

__global__ __launch_bounds__(64, 1) void lstm_last_kernel(
    const float* __restrict__ x,      // [B, T, 1]
    const float* __restrict__ W_ih,   // [4H, 1]
    const float* __restrict__ W_hh,   // [4H, H]
    const float* __restrict__ b_ih,   // [4H]
    const float* __restrict__ b_hh,   // [4H]
    float* __restrict__ out)          // [B, H]
{
    const int b    = blockIdx.x;
    const int l    = threadIdx.x;   // 0..63
    const int k    = l & 31;        // hidden unit index
    const int half = l >> 5;        // 0: rows (i_k, g_k); 1: rows (f_k, o_k)
    const int row0 = l;             // i_k (half0) or f_k (half1)
    const int row1 = l + 64;        // g_k (half0) or o_k (half1)

    __shared__ float x_lds[TSEQ + 4];
    __shared__ float h_lds[64];     // slots 0..31 = h, slots 32..63 = half0 trash pad

    // ---- one-time staging: x row into LDS (float4, coalesced) ----
    const float4* xrow4 = (const float4*)(x + (size_t)b * TSEQ);
    float4* xl4 = (float4*)x_lds;
    #pragma unroll
    for (int j = 0; j < (TSEQ / 4) / 64; ++j)   // 8 iters
        xl4[j * 64 + l] = xrow4[j * 64 + l];
    if (l == 0) x_lds[TSEQ] = 0.0f;
    h_lds[l] = 0.0f;                // h0 = 0 (and zero the pad)

    // ---- one-time: weights as j-pairs, PRE-SCALED ----
    // dot0 (i/f): * -log2e          => sigmoid = rcp(1+exp2(d0))
    // dot1 g:     * -2log2e         => sigma(2g) = rcp(1+exp2(d1))
    // dot1 o:     * -log2e          => sigmoid
    const float sc0 = NL2E;
    const float sc1 = half ? NL2E : 2.0f * NL2E;

    v2f wp0[HSZ/2], wp1[HSZ/2];
    #pragma unroll
    for (int j = 0; j < HSZ; j += 4) {
        float4 a  = *(const float4*)(W_hh + row0 * HSZ + j);
        float4 c4 = *(const float4*)(W_hh + row1 * HSZ + j);
        wp0[j/2]     = make2(a.x * sc0,  a.y * sc0);
        wp0[j/2 + 1] = make2(a.z * sc0,  a.w * sc0);
        wp1[j/2]     = make2(c4.x * sc1, c4.y * sc1);
        wp1[j/2 + 1] = make2(c4.z * sc1, c4.w * sc1);
    }
    const v2f wxp0   = make2(W_ih[row0] * sc0, 0.0f);
    const v2f wxp1   = make2(W_ih[row1] * sc1, 0.0f);
    const v2f biasp0 = make2((b_ih[row0] + b_hh[row0]) * sc0, 0.0f);
    const v2f biasp1 = make2((b_ih[row1] + b_hh[row1]) * sc1, 0.0f);

    // a1' for half0 = S*tanh(g) with S = 2*log2e = -2*NL2E:
    //   a1' = 2S*sigma(2g) - S  => s1mul = -4*NL2E, s1add = 2*NL2E
    // a1 for half1 = sigmoid(o) => s1mul = 1, s1add = 0
    const float s1mul = half ? 1.0f : -4.0f * NL2E;
    const float s1add = half ? 0.0f :  2.0f * NL2E;

    float cc = 0.0f;   // scaled cell state: 2*log2e * c
    float hk = 0.0f;   // h_k valid in lanes 32..63

    // All-lane LDS write address: half1 -> real slot (l-32), half0 -> pad (l+32).
    const int waddr = l ^ 32;

    __syncthreads();   // x_lds + h_lds ready
    float xt = x_lds[0];

    #pragma unroll 1
    for (int t = 0; t < TSEQ; ++t) {
        // ---- broadcast h: 8x ds_read_b128, uniform address (no conflicts).
        //      Pairs land directly in VGPR pairs for pk_fma (no movs, no SGPRs).
        //      Same-wave DS pipe is in-order: sees last iteration's write. ----
        v2f hp[HSZ/2];
        #pragma unroll
        for (int m = 0; m < 8; ++m) {
            float4 v4 = ((const float4*)h_lds)[m];
            hp[2*m]   = make2(v4.x, v4.y);
            hp[2*m+1] = make2(v4.z, v4.w);
        }

        float xt_next = x_lds[t + 1];   // prefetch

        v2f xtp = make2(xt, xt);

        // ---- two length-32 dots as packed j-pairs, 4 chains each ----
        v2f q0 = PKFMA(wxp0, xtp, biasp0);
        v2f q1 = make2(0.f, 0.f), q2 = make2(0.f, 0.f), q3 = make2(0.f, 0.f);
        v2f u0 = PKFMA(wxp1, xtp, biasp1);
        v2f u1 = make2(0.f, 0.f), u2 = make2(0.f, 0.f), u3 = make2(0.f, 0.f);
        #pragma unroll
        for (int m = 0; m < HSZ/2; m += 4) {
            q0 = PKFMA(wp0[m],   hp[m],   q0);
            q1 = PKFMA(wp0[m+1], hp[m+1], q1);
            q2 = PKFMA(wp0[m+2], hp[m+2], q2);
            q3 = PKFMA(wp0[m+3], hp[m+3], q3);
            u0 = PKFMA(wp1[m],   hp[m],   u0);
            u1 = PKFMA(wp1[m+1], hp[m+1], u1);
            u2 = PKFMA(wp1[m+2], hp[m+2], u2);
            u3 = PKFMA(wp1[m+3], hp[m+3], u3);
        }
        v2f r0 = (q0 + q1) + (q2 + q3);
        v2f r1 = (u0 + u1) + (u2 + u3);
        float d0 = r0.x + r0.y;   // i (half0) / f (half1), pre-scaled
        float d1 = r1.x + r1.y;   // g (half0) / o (half1), pre-scaled

        float a0 = hw_rcp(1.0f + hw_exp2(d0));                     // sigmoid(i/f)
        float a1 = fmaf(s1mul, hw_rcp(1.0f + hw_exp2(d1)), s1add); // S*tanh(g) / sigm(o)
        float m2a1 = -2.0f * a1;                                   // off-chain

        // half0 piece: i * (S*tanh(g)) = S*(i*g); half1 piece: f * cc_old.
        // Cross-half SUM = cc_new (= S*c_new) in every lane.
        float v  = a0 * (half ? cc : a1);
        float cn = half_sum(v);
        cc = cn;

        // tanh(c) = 1 - 2*rcp(1+exp2(cc));  hk = a1*tanh(c) = fma(-2a1, r, a1)
        float r = hw_rcp(1.0f + hw_exp2(cn));
        hk = fmaf(m2a1, r, a1);   // valid (o*tanh(c)) in lanes 32..63

        // all-lane write: half1 -> real slots, half0 -> pad (no exec churn)
        h_lds[waddr] = hk;

        xt = xt_next;
    }

    if (half) out[b * HSZ + k] = hk;
}

extern "C" void kernel_launch(void* const* d_in, const int* in_sizes, int n_in,
                              void* d_out, int out_size, void* d_ws, size_t ws_size,
                              hipStream_t stream) {
    const float* x    = (const float*)d_in[0];
    const float* W_ih = (const float*)d_in[1];
    const float* W_hh = (const float*)d_in[2];
    const float* b_ih = (const float*)d_in[3];
    const float* b_hh = (const float*)d_in[4];
    float* out = (float*)d_out;

    lstm_last_kernel<<<NBATCH, 64, 0, stream>>>(x, W_ih, W_hh, b_ih, b_hh, out);
}